// Round 12
// baseline (44.398 us; speedup 1.0000x reference)
//
#include <hip/hip_runtime.h>

#define H 1024
#define W 1024
#define TILE 32
#define SR 40    // hsum rows: TILE + 8 (halo4)
#define SC 36    // hsum cols: TILE + 4
#define VR 36    // vw rows:   TILE + 4
#define VC 36    // vw cols:   TILE + 4

// LDS: s_su 40*36*8 = 11520 B + s_vw 36*36*8 = 10368 B -> 21888 B -> 7 blocks/CU.

__device__ __forceinline__ unsigned bf16rne(float f) {   // fp32 -> bf16 bits (RNE)
    unsigned u = __float_as_uint(f);
    return (u + 0x7FFFu + ((u >> 16) & 1u)) >> 16;
}
__device__ __forceinline__ float bf16lo(unsigned u) { return __uint_as_float(u << 16); }
__device__ __forceinline__ float bf16hi(unsigned u) { return __uint_as_float(u & 0xFFFF0000u); }

__global__ __launch_bounds__(256)
void kuwahara_kernel(const float* __restrict__ inp, float* __restrict__ out) {
    __shared__ float2 s_su[SR][SC];   // (hsum luma, hsum luma^2), halo4 rows, fp32
    __shared__ uint2  s_vw[VR][VC];   // bf16: x = r|g<<16, y = b|w<<16 (w by stage 3)

    const int tid = threadIdx.x;

    // ---- XCD-aware swizzle: each XCD owns 512 contiguous tiles (x-fastest) ----
    unsigned wg  = blockIdx.x;          // grid = 4096 linear blocks
    unsigned lin = (wg & 7u) * 512u + (wg >> 3);
    const int n  = lin >> 10;
    const int y0 = ((lin >> 5) & 31) * TILE;
    const int x0 = (lin & 31) * TILE;

    const float* __restrict__ pR = inp + ((size_t)(4*n + 0) << 20);
    const float* __restrict__ pG = inp + ((size_t)(4*n + 1) << 20);
    const float* __restrict__ pB = inp + ((size_t)(4*n + 2) << 20);
    const float* __restrict__ pK = inp + ((size_t)(4*n + 3) << 20);

    const int tx  = tid & 31;   // column within tile
    const int tg  = tid >> 5;   // row-group: owns rows 4*tg .. 4*tg+3
    const int gx  = x0 + tx;
    const int pr0 = tg << 2;

    // ---- k at this thread's 4 output pixels (fp32 exact; L1/L2-resident) ----
    float kc[4];
#pragma unroll
    for (int p = 0; p < 4; ++p)
        kc[p] = pK[((y0 + pr0 + p) << 10) + gx];

    // ---- stage 1 (fully fused, SINGLE load of rgb per halo pixel):
    // luma + horizontal 5-sums via __shfl_down, AND bf16 s_vw fill from the
    // same registers. 10 lanes/row (one 4-px quad each); 6 rows/wave; 2 passes.
    // k is NOT staged: stage 3 reads it from global (L2 hit).
    {
        const int lane = tid & 63;
        const int wid  = tid >> 6;
        const int rloc = lane / 10;            // 0..5 active, 6 idle
        const int qq   = lane - rloc * 10;     // quad index 0..9
        const int gcs  = x0 - 4 + (qq << 2);
#pragma unroll
        for (int pass = 0; pass < 2; ++pass) {
            int row = pass * 24 + wid * 6 + rloc;
            bool act = (rloc < 6) && (row < SR);
            bool vwrow = act && (row >= 2) && (row < SR - 2);
            float l0 = 0.f, l1 = 0.f, l2 = 0.f, l3 = 0.f;
            float rr[4], gg[4], bb[4];
            if (act) {
                int gy = y0 - 4 + row;
                int cy = min(max(gy, 0), H - 1);
                const int base = cy << 10;
                if (gcs >= 0 && gcs <= W - 4) {         // x-interior: vector
                    float4 r4 = *(const float4*)(pR + base + gcs);
                    float4 g4 = *(const float4*)(pG + base + gcs);
                    float4 b4 = *(const float4*)(pB + base + gcs);
                    rr[0]=r4.x; rr[1]=r4.y; rr[2]=r4.z; rr[3]=r4.w;
                    gg[0]=g4.x; gg[1]=g4.y; gg[2]=g4.z; gg[3]=g4.w;
                    bb[0]=b4.x; bb[1]=b4.y; bb[2]=b4.z; bb[3]=b4.w;
                } else {                                 // x-border: clamped
#pragma unroll
                    for (int e = 0; e < 4; ++e) {
                        int cx = min(max(gcs + e, 0), W - 1);
                        rr[e] = pR[base + cx]; gg[e] = pG[base + cx];
                        bb[e] = pB[base + cx];
                    }
                }
                bool rowIn = ((unsigned)gy < (unsigned)H);
                float lv[4];
#pragma unroll
                for (int e = 0; e < 4; ++e) {
                    bool colIn = ((unsigned)(gcs + e) < (unsigned)W);
                    lv[e] = (rowIn && colIn)
                        ? fmaf(0.2126f, rr[e], fmaf(0.7152f, gg[e], 0.0722f * bb[e]))
                        : 0.0f;                          // zero pad rows AND cols
                }
                l0 = lv[0]; l1 = lv[1]; l2 = lv[2]; l3 = lv[3];
            }
            // neighbor quad's luma (same row: qq<=8 pulls from qq+1)
            float l4 = __shfl_down(l0, 1, 64);
            float l5 = __shfl_down(l1, 1, 64);
            float l6 = __shfl_down(l2, 1, 64);
            float l7 = __shfl_down(l3, 1, 64);
            if (act && qq < 9) {
                float s0 = ((l0 + l1) + (l2 + l3)) + l4;
                float s1 = s0 - l0 + l5;
                float s2 = s1 - l1 + l6;
                float s3 = s2 - l2 + l7;
                float m0=l0*l0, m1=l1*l1, m2=l2*l2, m3=l3*l3;
                float m4=l4*l4, m5=l5*l5, m6=l6*l6, m7=l7*l7;
                float u0 = ((m0 + m1) + (m2 + m3)) + m4;
                float u1 = u0 - m0 + m5;
                float u2 = u1 - m1 + m6;
                float u3 = u2 - m2 + m7;
                int c = qq << 2;
                *(float4*)&s_su[row][c]     = make_float4(s0, u0, s1, u1);
                *(float4*)&s_su[row][c + 2] = make_float4(s2, u2, s3, u3);
            }
            if (vwrow) {                                 // bf16 s_vw, SAME regs
#pragma unroll
                for (int e = 0; e < 4; ++e) {
                    int iv = (qq << 2) + e - 2;
                    if ((unsigned)iv < (unsigned)VC)
                        s_vw[row - 2][iv] = make_uint2(
                            bf16rne(rr[e]) | (bf16rne(gg[e]) << 16),
                            bf16rne(bb[e]));             // hi16 filled by stage 3
                }
            }
        }
    }
    __syncthreads();

    // ---- stage 3: vertical 5-sum -> variance -> weight (b16 store). 2-wide ----
    // 648 tasks: j2 in [0,36), q in [0,18); k read from GLOBAL (L2 hit).
    for (int idx = tid; idx < VR * 18; idx += 256) {
        int j2 = idx / 18, q = idx - j2 * 18;
        int c  = q << 1;
        int gyc = min(max(y0 - 2 + j2, 0), H - 1);  // clamped window center row
        int js  = gyc - y0 + 2;
        int g0  = x0 - 2 + c;                       // unclamped center col (e=0)
        const int kbase = gyc << 10;
        float s_a, u_a, s_b, u_b;
        float k_a, k_b;
        if (g0 >= 0 && g0 + 1 <= W - 1) {           // both cols interior
            float4 acc = make_float4(0.f, 0.f, 0.f, 0.f);
#pragma unroll
            for (int r = 0; r < 5; ++r) {
                float4 v = *(const float4*)&s_su[js + r][c];
                acc.x += v.x; acc.y += v.y; acc.z += v.z; acc.w += v.w;
            }
            s_a = acc.x; u_a = acc.y; s_b = acc.z; u_b = acc.w;
            k_a = pK[kbase + g0];
            k_b = pK[kbase + g0 + 1];
        } else {                                    // x-border: clamped scalar
            float sv[2], uv[2], kv[2];
#pragma unroll
            for (int e = 0; e < 2; ++e) {
                int gxc = min(max(g0 + e, 0), W - 1);
                int is  = gxc - x0 + 2;
                float ss = 0.f, sq = 0.f;
#pragma unroll
                for (int r = 0; r < 5; ++r) {
                    float2 v = s_su[js + r][is];
                    ss += v.x; sq += v.y;
                }
                sv[e] = ss; uv[e] = sq;
                kv[e] = pK[kbase + gxc];
            }
            s_a = sv[0]; u_a = uv[0]; s_b = sv[1]; u_b = uv[1];
            k_a = kv[0]; k_b = kv[1];
        }
        {
            float mean = s_a * 0.04f, msq = u_a * 0.04f;
            float var  = fabsf(msq - mean * mean);
            float wv   = __expf(-var * 64.0f * k_a);
            ((unsigned short*)&s_vw[j2][c])[3] = (unsigned short)bf16rne(wv);
        }
        {
            float mean = s_b * 0.04f, msq = u_b * 0.04f;
            float var  = fabsf(msq - mean * mean);
            float wv   = __expf(-var * 64.0f * k_b);
            ((unsigned short*)&s_vw[j2][c + 1])[3] = (unsigned short)bf16rne(wv);
        }
    }
    __syncthreads();

    // ---- spatial-falloff constants (late, short live ranges) ----
    float t1[4], t4[4];
#pragma unroll
    for (int p = 0; p < 4; ++p) {
        float t = __expf(-2.56f * (1.0f - kc[p]));   // t^(dx^2+dy^2) base
        t1[p] = t;
        t4[p] = (t * t) * (t * t);
    }

    // ---- stage 4: 25-tap filter; b64 taps, factorized row sums, 4 px/thread ----
    float accR[4], accG[4], accB[4], accW[4];
#pragma unroll
    for (int p = 0; p < 4; ++p) { accR[p] = accG[p] = accB[p] = accW[p] = 0.f; }

#pragma unroll
    for (int r = 0; r < 8; ++r) {
        const uint2* row = &s_vw[pr0 + r][tx];       // single base, imm offsets
        uint2 c0 = row[0], c1 = row[1], c2 = row[2], c3 = row[3], c4 = row[4];
        float a0x = bf16lo(c0.x), a0y = bf16hi(c0.x), a0z = bf16lo(c0.y), a0w = bf16hi(c0.y);
        float a1x = bf16lo(c1.x), a1y = bf16hi(c1.x), a1z = bf16lo(c1.y), a1w = bf16hi(c1.y);
        float a2x = bf16lo(c2.x), a2y = bf16hi(c2.x), a2z = bf16lo(c2.y), a2w = bf16hi(c2.y);
        float a3x = bf16lo(c3.x), a3y = bf16hi(c3.x), a3z = bf16lo(c3.y), a3w = bf16hi(c3.y);
        float a4x = bf16lo(c4.x), a4y = bf16hi(c4.x), a4z = bf16lo(c4.y), a4w = bf16hi(c4.y);
        // partial sums by |dx|: S0 (dx=0), S1 (|dx|=1), S2 (|dx|=2)
        float S0w = a2w;
        float S0x = a2w * a2x, S0y = a2w * a2y, S0z = a2w * a2z;
        float S1w = a1w + a3w;
        float S1x = a1w * a1x + a3w * a3x;
        float S1y = a1w * a1y + a3w * a3y;
        float S1z = a1w * a1z + a3w * a3z;
        float S2w = a0w + a4w;
        float S2x = a0w * a0x + a4w * a4x;
        float S2y = a0w * a0y + a4w * a4y;
        float S2z = a0w * a0z + a4w * a4z;
#pragma unroll
        for (int p = 0; p < 4; ++p) {
            const int dy = r - 2 - p;                // compile-time after unroll
            if (dy < -2 || dy > 2) continue;
            const int ady = dy < 0 ? -dy : dy;
            float rw = S0w + t1[p] * S1w + t4[p] * S2w;
            float rx = S0x + t1[p] * S1x + t4[p] * S2x;
            float ry = S0y + t1[p] * S1y + t4[p] * S2y;
            float rz = S0z + t1[p] * S1z + t4[p] * S2z;
            if (ady == 0) {
                accR[p] += rx; accG[p] += ry; accB[p] += rz; accW[p] += rw;
            } else {
                float rf = (ady == 1) ? t1[p] : t4[p];
                accR[p] += rf * rx; accG[p] += rf * ry;
                accB[p] += rf * rz; accW[p] += rf * rw;
            }
        }
    }

    float* __restrict__ oR = out + ((size_t)(3*n + 0) << 20);
    float* __restrict__ oG = out + ((size_t)(3*n + 1) << 20);
    float* __restrict__ oB = out + ((size_t)(3*n + 2) << 20);
#pragma unroll
    for (int p = 0; p < 4; ++p) {
        uint2 cc = s_vw[pr0 + p + 2][tx + 2];        // center rgb (bf16, 8 B)
        float cx_ = bf16lo(cc.x), cy_ = bf16hi(cc.x), cz_ = bf16lo(cc.y);
        float cb = 16.0f + kc[p] * (0.001f - 16.0f); // center boost
        accR[p] += cb * cx_;
        accG[p] += cb * cy_;
        accB[p] += cb * cz_;
        accW[p] += cb;
        float inv = __builtin_amdgcn_rcpf(accW[p]);
        int off = ((y0 + pr0 + p) << 10) + gx;
        oR[off] = cx_ + kc[p] * (accR[p] * inv - cx_);
        oG[off] = cy_ + kc[p] * (accG[p] * inv - cy_);
        oB[off] = cz_ + kc[p] * (accB[p] * inv - cz_);
    }
}

extern "C" void kernel_launch(void* const* d_in, const int* in_sizes, int n_in,
                              void* d_out, int out_size, void* d_ws, size_t ws_size,
                              hipStream_t stream) {
    const float* inp = (const float*)d_in[0];
    float* out = (float*)d_out;
    hipLaunchKernelGGL(kuwahara_kernel, dim3(4096), dim3(256), 0, stream, inp, out);
}

// Round 13
// 36.724 us; speedup vs baseline: 1.2090x; 1.2090x over previous
//
#include <hip/hip_runtime.h>

#define H 1024
#define W 1024
#define TILE 32
#define SR 40    // hsum rows: TILE + 8 (halo4)
#define SC 36    // hsum cols: TILE + 4
#define VR 36    // vw rows:   TILE + 4
#define VC 36    // vw cols:   TILE + 4

// LDS: s_su 40*36*8 = 11520 B + s_vw 36*36*16 = 20736 B -> 32256 B -> 5 blocks/CU.

__global__ __launch_bounds__(256)
void kuwahara_kernel(const float* __restrict__ inp, float* __restrict__ out) {
    __shared__ float2 s_su[SR][SC];   // (hsum luma, hsum luma^2), halo4 rows
    __shared__ float4 s_vw[VR][VC];   // (r, g, b, k->weight), edge-replicated

    const int tid = threadIdx.x;

    // ---- XCD-aware swizzle: each XCD owns 512 contiguous tiles (x-fastest) ----
    unsigned wg  = blockIdx.x;          // grid = 4096 linear blocks
    unsigned lin = (wg & 7u) * 512u + (wg >> 3);
    const int n  = lin >> 10;
    const int y0 = ((lin >> 5) & 31) * TILE;
    const int x0 = (lin & 31) * TILE;

    const float* __restrict__ pR = inp + ((size_t)(4*n + 0) << 20);
    const float* __restrict__ pG = inp + ((size_t)(4*n + 1) << 20);
    const float* __restrict__ pB = inp + ((size_t)(4*n + 2) << 20);
    const float* __restrict__ pK = inp + ((size_t)(4*n + 3) << 20);

    const int tx  = tid & 31;   // column within tile
    const int tg  = tid >> 5;   // row-group: owns rows 4*tg .. 4*tg+3
    const int gx  = x0 + tx;
    const int pr0 = tg << 2;

    // ---- k at this thread's 4 output pixels (fp32 exact; L1/L2-resident) ----
    float kc[4];
#pragma unroll
    for (int p = 0; p < 4; ++p)
        kc[p] = pK[((y0 + pr0 + p) << 10) + gx];

    // ---- stage 1 (fully fused, SINGLE load of rgbk per halo pixel):
    // luma + horizontal 5-sums via __shfl_down, AND s_vw fill from the same
    // registers. 10 lanes/row (one 4-px quad each); 6 rows/wave; 2 passes.
    {
        const int lane = tid & 63;
        const int wid  = tid >> 6;
        const int rloc = lane / 10;            // 0..5 active, 6 idle
        const int qq   = lane - rloc * 10;     // quad index 0..9
        const int gcs  = x0 - 4 + (qq << 2);
#pragma unroll
        for (int pass = 0; pass < 2; ++pass) {
            int row = pass * 24 + wid * 6 + rloc;
            bool act = (rloc < 6) && (row < SR);
            bool vwrow = act && (row >= 2) && (row < SR - 2);
            float l0 = 0.f, l1 = 0.f, l2 = 0.f, l3 = 0.f;
            float rr[4], gg[4], bb[4], kk[4];
            if (act) {
                int gy = y0 - 4 + row;
                int cy = min(max(gy, 0), H - 1);
                const int base = cy << 10;
                if (gcs >= 0 && gcs <= W - 4) {         // x-interior: vector
                    float4 r4 = *(const float4*)(pR + base + gcs);
                    float4 g4 = *(const float4*)(pG + base + gcs);
                    float4 b4 = *(const float4*)(pB + base + gcs);
                    rr[0]=r4.x; rr[1]=r4.y; rr[2]=r4.z; rr[3]=r4.w;
                    gg[0]=g4.x; gg[1]=g4.y; gg[2]=g4.z; gg[3]=g4.w;
                    bb[0]=b4.x; bb[1]=b4.y; bb[2]=b4.z; bb[3]=b4.w;
                    if (vwrow) {
                        float4 k4 = *(const float4*)(pK + base + gcs);
                        kk[0]=k4.x; kk[1]=k4.y; kk[2]=k4.z; kk[3]=k4.w;
                    }
                } else {                                 // x-border: clamped
#pragma unroll
                    for (int e = 0; e < 4; ++e) {
                        int cx = min(max(gcs + e, 0), W - 1);
                        rr[e] = pR[base + cx]; gg[e] = pG[base + cx];
                        bb[e] = pB[base + cx];
                        kk[e] = vwrow ? pK[base + cx] : 0.f;
                    }
                }
                bool rowIn = ((unsigned)gy < (unsigned)H);
                float lv[4];
#pragma unroll
                for (int e = 0; e < 4; ++e) {
                    bool colIn = ((unsigned)(gcs + e) < (unsigned)W);
                    lv[e] = (rowIn && colIn)
                        ? fmaf(0.2126f, rr[e], fmaf(0.7152f, gg[e], 0.0722f * bb[e]))
                        : 0.0f;                          // zero pad rows AND cols
                }
                l0 = lv[0]; l1 = lv[1]; l2 = lv[2]; l3 = lv[3];
            }
            // neighbor quad's luma (same row: qq<=8 pulls from qq+1)
            float l4 = __shfl_down(l0, 1, 64);
            float l5 = __shfl_down(l1, 1, 64);
            float l6 = __shfl_down(l2, 1, 64);
            float l7 = __shfl_down(l3, 1, 64);
            if (act && qq < 9) {
                float s0 = ((l0 + l1) + (l2 + l3)) + l4;
                float s1 = s0 - l0 + l5;
                float s2 = s1 - l1 + l6;
                float s3 = s2 - l2 + l7;
                float m0=l0*l0, m1=l1*l1, m2=l2*l2, m3=l3*l3;
                float m4=l4*l4, m5=l5*l5, m6=l6*l6, m7=l7*l7;
                float u0 = ((m0 + m1) + (m2 + m3)) + m4;
                float u1 = u0 - m0 + m5;
                float u2 = u1 - m1 + m6;
                float u3 = u2 - m2 + m7;
                int c = qq << 2;
                *(float4*)&s_su[row][c]     = make_float4(s0, u0, s1, u1);
                *(float4*)&s_su[row][c + 2] = make_float4(s2, u2, s3, u3);
            }
            if (vwrow) {                // s_vw from SAME regs; rotated write
#pragma unroll                          // order spreads the 16-bank qq stride
                for (int e = 0; e < 4; ++e) {
                    int er = (e + qq) & 3;
                    int iv = (qq << 2) + er - 2;
                    if ((unsigned)iv < (unsigned)VC)
                        s_vw[row - 2][iv] = make_float4(rr[er], gg[er], bb[er], kk[er]);
                }
            }
        }
    }
    __syncthreads();

    // ---- stage 3: vertical 5-sum -> variance -> weight. 2x2 paired tasks ----
    // 324 tasks: j2p in [0,18), q in [0,18). Rows 2*j2p, 2*j2p+1 share 4 of 6
    // s_su rows: 6 b128 reads per 4 weights (was 10).
    for (int idx = tid; idx < 324; idx += 256) {
        int j2p = idx / 18, q = idx - j2p * 18;
        int j2a = j2p << 1, j2b = j2a + 1;
        int c   = q << 1;
        int g0  = x0 - 2 + c;
        bool okx = (g0 >= 0) && (g0 + 1 <= W - 1);
        bool oky = (y0 - 2 + j2a >= 0) && (y0 - 2 + j2b <= H - 1);
        if (okx && oky) {                       // fast: unclamped 2x2 patch
            float4 r0 = *(const float4*)&s_su[j2a + 0][c];
            float4 r1 = *(const float4*)&s_su[j2a + 1][c];
            float4 r2 = *(const float4*)&s_su[j2a + 2][c];
            float4 r3 = *(const float4*)&s_su[j2a + 3][c];
            float4 r4 = *(const float4*)&s_su[j2a + 4][c];
            float4 r5 = *(const float4*)&s_su[j2a + 5][c];
            float sa0 = (((r0.x + r1.x) + (r2.x + r3.x)) + r4.x);
            float ua0 = (((r0.y + r1.y) + (r2.y + r3.y)) + r4.y);
            float sa1 = (((r0.z + r1.z) + (r2.z + r3.z)) + r4.z);
            float ua1 = (((r0.w + r1.w) + (r2.w + r3.w)) + r4.w);
            float sb0 = sa0 - r0.x + r5.x;
            float ub0 = ua0 - r0.y + r5.y;
            float sb1 = sa1 - r0.z + r5.z;
            float ub1 = ua1 - r0.w + r5.w;
            {
                float mean = sa0 * 0.04f, msq = ua0 * 0.04f;
                float var  = fabsf(msq - mean * mean);
                s_vw[j2a][c].w = __expf(-var * 64.0f * s_vw[j2a][c].w);
            }
            {
                float mean = sa1 * 0.04f, msq = ua1 * 0.04f;
                float var  = fabsf(msq - mean * mean);
                s_vw[j2a][c + 1].w = __expf(-var * 64.0f * s_vw[j2a][c + 1].w);
            }
            {
                float mean = sb0 * 0.04f, msq = ub0 * 0.04f;
                float var  = fabsf(msq - mean * mean);
                s_vw[j2b][c].w = __expf(-var * 64.0f * s_vw[j2b][c].w);
            }
            {
                float mean = sb1 * 0.04f, msq = ub1 * 0.04f;
                float var  = fabsf(msq - mean * mean);
                s_vw[j2b][c + 1].w = __expf(-var * 64.0f * s_vw[j2b][c + 1].w);
            }
        } else {                                // border: per-output scalar
#pragma unroll
            for (int jj = 0; jj < 2; ++jj) {
                int j2 = j2a + jj;
                int gyc = min(max(y0 - 2 + j2, 0), H - 1);
                int js  = gyc - y0 + 2;
#pragma unroll
                for (int e = 0; e < 2; ++e) {
                    int is = min(max(g0 + e, 0), W - 1) - x0 + 2;
                    float ss = 0.f, sq = 0.f;
#pragma unroll
                    for (int r = 0; r < 5; ++r) {
                        float2 v = s_su[js + r][is];
                        ss += v.x; sq += v.y;
                    }
                    float mean = ss * 0.04f, msq = sq * 0.04f;
                    float var  = fabsf(msq - mean * mean);
                    s_vw[j2][c + e].w = __expf(-var * 64.0f * s_vw[j2][c + e].w);
                }
            }
        }
    }
    __syncthreads();

    // ---- spatial-falloff constants (late, short live ranges) ----
    float t1[4], t4[4];
#pragma unroll
    for (int p = 0; p < 4; ++p) {
        float t = __expf(-2.56f * (1.0f - kc[p]));   // t^(dx^2+dy^2) base
        t1[p] = t;
        t4[p] = (t * t) * (t * t);
    }

    // ---- stage 4: 25-tap filter; factorized row sums shared across 4 px ----
    float accR[4], accG[4], accB[4], accW[4];
    float ctrR[4], ctrG[4], ctrB[4];
#pragma unroll
    for (int p = 0; p < 4; ++p) { accR[p] = accG[p] = accB[p] = accW[p] = 0.f; }

#pragma unroll
    for (int r = 0; r < 8; ++r) {
        const float4* row = &s_vw[pr0 + r][tx];      // single base, imm offsets
        float4 a0 = row[0], a1 = row[1], a2 = row[2], a3 = row[3], a4 = row[4];
        // partial sums by |dx|: S0 (dx=0), S1 (|dx|=1), S2 (|dx|=2)
        float S0w = a2.w;
        float S0x = a2.w * a2.x, S0y = a2.w * a2.y, S0z = a2.w * a2.z;
        float S1w = a1.w + a3.w;
        float S1x = a1.w * a1.x + a3.w * a3.x;
        float S1y = a1.w * a1.y + a3.w * a3.y;
        float S1z = a1.w * a1.z + a3.w * a3.z;
        float S2w = a0.w + a4.w;
        float S2x = a0.w * a0.x + a4.w * a4.x;
        float S2y = a0.w * a0.y + a4.w * a4.y;
        float S2z = a0.w * a0.z + a4.w * a4.z;
#pragma unroll
        for (int p = 0; p < 4; ++p) {
            const int dy = r - 2 - p;                // compile-time after unroll
            if (dy < -2 || dy > 2) continue;
            const int ady = dy < 0 ? -dy : dy;
            float rw = S0w + t1[p] * S1w + t4[p] * S2w;
            float rx = S0x + t1[p] * S1x + t4[p] * S2x;
            float ry = S0y + t1[p] * S1y + t4[p] * S2y;
            float rz = S0z + t1[p] * S1z + t4[p] * S2z;
            if (ady == 0) {                          // center row: capture rgb
                ctrR[p] = a2.x; ctrG[p] = a2.y; ctrB[p] = a2.z;
                accR[p] += rx; accG[p] += ry; accB[p] += rz; accW[p] += rw;
            } else {
                float rf = (ady == 1) ? t1[p] : t4[p];
                accR[p] += rf * rx; accG[p] += rf * ry;
                accB[p] += rf * rz; accW[p] += rf * rw;
            }
        }
    }

    float* __restrict__ oR = out + ((size_t)(3*n + 0) << 20);
    float* __restrict__ oG = out + ((size_t)(3*n + 1) << 20);
    float* __restrict__ oB = out + ((size_t)(3*n + 2) << 20);
#pragma unroll
    for (int p = 0; p < 4; ++p) {
        float cb = 16.0f + kc[p] * (0.001f - 16.0f); // center boost
        accR[p] += cb * ctrR[p];
        accG[p] += cb * ctrG[p];
        accB[p] += cb * ctrB[p];
        accW[p] += cb;
        float inv = __builtin_amdgcn_rcpf(accW[p]);
        int off = ((y0 + pr0 + p) << 10) + gx;
        oR[off] = ctrR[p] + kc[p] * (accR[p] * inv - ctrR[p]);
        oG[off] = ctrG[p] + kc[p] * (accG[p] * inv - ctrG[p]);
        oB[off] = ctrB[p] + kc[p] * (accB[p] * inv - ctrB[p]);
    }
}

extern "C" void kernel_launch(void* const* d_in, const int* in_sizes, int n_in,
                              void* d_out, int out_size, void* d_ws, size_t ws_size,
                              hipStream_t stream) {
    const float* inp = (const float*)d_in[0];
    float* out = (float*)d_out;
    hipLaunchKernelGGL(kuwahara_kernel, dim3(4096), dim3(256), 0, stream, inp, out);
}

// Round 14
// 36.171 us; speedup vs baseline: 1.2275x; 1.0153x over previous
//
#include <hip/hip_runtime.h>

#define H 1024
#define W 1024
#define TILE 32
#define SR 40    // hsum rows: TILE + 8 (halo4)
#define SC 36    // hsum cols: TILE + 4
#define VR 36    // vw rows:   TILE + 4
#define VC 36    // vw cols:   TILE + 4

// LDS: s_su 40*36*8 = 11520 B + s_vw 36*36*16 = 20736 B -> 32256 B -> 5 blocks/CU.

__global__ __launch_bounds__(256)
void kuwahara_kernel(const float* __restrict__ inp, float* __restrict__ out) {
    __shared__ float2 s_su[SR][SC];   // (hsum luma, hsum luma^2), halo4 rows
    __shared__ float4 s_vw[VR][VC];   // (r, g, b, k->weight), edge-replicated

    const int tid = threadIdx.x;

    // ---- XCD-aware swizzle: each XCD owns 512 contiguous tiles (x-fastest) ----
    unsigned wg  = blockIdx.x;          // grid = 4096 linear blocks
    unsigned lin = (wg & 7u) * 512u + (wg >> 3);
    const int n  = lin >> 10;
    const int y0 = ((lin >> 5) & 31) * TILE;
    const int x0 = (lin & 31) * TILE;

    const float* __restrict__ pR = inp + ((size_t)(4*n + 0) << 20);
    const float* __restrict__ pG = inp + ((size_t)(4*n + 1) << 20);
    const float* __restrict__ pB = inp + ((size_t)(4*n + 2) << 20);
    const float* __restrict__ pK = inp + ((size_t)(4*n + 3) << 20);

    const int tx  = tid & 31;   // column within tile
    const int tg  = tid >> 5;   // row-group: owns rows 4*tg .. 4*tg+3
    const int gx  = x0 + tx;
    const int pr0 = tg << 2;

    // ---- k at this thread's 4 output pixels (fp32 exact; L1/L2-resident) ----
    float kc[4];
#pragma unroll
    for (int p = 0; p < 4; ++p)
        kc[p] = pK[((y0 + pr0 + p) << 10) + gx];

    // ---- stage 1 (fully fused, SINGLE load of rgbk per halo pixel):
    // luma + horizontal 5-sums via __shfl_down, AND s_vw fill from the same
    // registers. 10 lanes/row (one 4-px quad each); 6 rows/wave; 2 passes.
    {
        const int lane = tid & 63;
        const int wid  = tid >> 6;
        const int rloc = lane / 10;            // 0..5 active, 6 idle
        const int qq   = lane - rloc * 10;     // quad index 0..9
        const int gcs  = x0 - 4 + (qq << 2);
#pragma unroll
        for (int pass = 0; pass < 2; ++pass) {
            int row = pass * 24 + wid * 6 + rloc;
            bool act = (rloc < 6) && (row < SR);
            bool vwrow = act && (row >= 2) && (row < SR - 2);
            float l0 = 0.f, l1 = 0.f, l2 = 0.f, l3 = 0.f;
            float rr[4], gg[4], bb[4], kk[4];
            if (act) {
                int gy = y0 - 4 + row;
                int cy = min(max(gy, 0), H - 1);
                const int base = cy << 10;
                if (gcs >= 0 && gcs <= W - 4) {         // x-interior: vector
                    float4 r4 = *(const float4*)(pR + base + gcs);
                    float4 g4 = *(const float4*)(pG + base + gcs);
                    float4 b4 = *(const float4*)(pB + base + gcs);
                    rr[0]=r4.x; rr[1]=r4.y; rr[2]=r4.z; rr[3]=r4.w;
                    gg[0]=g4.x; gg[1]=g4.y; gg[2]=g4.z; gg[3]=g4.w;
                    bb[0]=b4.x; bb[1]=b4.y; bb[2]=b4.z; bb[3]=b4.w;
                    if (vwrow) {
                        float4 k4 = *(const float4*)(pK + base + gcs);
                        kk[0]=k4.x; kk[1]=k4.y; kk[2]=k4.z; kk[3]=k4.w;
                    }
                } else {                                 // x-border: clamped
#pragma unroll
                    for (int e = 0; e < 4; ++e) {
                        int cx = min(max(gcs + e, 0), W - 1);
                        rr[e] = pR[base + cx]; gg[e] = pG[base + cx];
                        bb[e] = pB[base + cx];
                        kk[e] = vwrow ? pK[base + cx] : 0.f;
                    }
                }
                bool rowIn = ((unsigned)gy < (unsigned)H);
                float lv[4];
#pragma unroll
                for (int e = 0; e < 4; ++e) {
                    bool colIn = ((unsigned)(gcs + e) < (unsigned)W);
                    lv[e] = (rowIn && colIn)
                        ? fmaf(0.2126f, rr[e], fmaf(0.7152f, gg[e], 0.0722f * bb[e]))
                        : 0.0f;                          // zero pad rows AND cols
                }
                l0 = lv[0]; l1 = lv[1]; l2 = lv[2]; l3 = lv[3];
            }
            // neighbor quad's luma (same row: qq<=8 pulls from qq+1)
            float l4 = __shfl_down(l0, 1, 64);
            float l5 = __shfl_down(l1, 1, 64);
            float l6 = __shfl_down(l2, 1, 64);
            float l7 = __shfl_down(l3, 1, 64);
            if (act && qq < 9) {
                float s0 = ((l0 + l1) + (l2 + l3)) + l4;
                float s1 = s0 - l0 + l5;
                float s2 = s1 - l1 + l6;
                float s3 = s2 - l2 + l7;
                float m0=l0*l0, m1=l1*l1, m2=l2*l2, m3=l3*l3;
                float m4=l4*l4, m5=l5*l5, m6=l6*l6, m7=l7*l7;
                float u0 = ((m0 + m1) + (m2 + m3)) + m4;
                float u1 = u0 - m0 + m5;
                float u2 = u1 - m1 + m6;
                float u3 = u2 - m2 + m7;
                int c = qq << 2;
                *(float4*)&s_su[row][c]     = make_float4(s0, u0, s1, u1);
                *(float4*)&s_su[row][c + 2] = make_float4(s2, u2, s3, u3);
            }
            if (vwrow) {                // s_vw from SAME regs; rotated write
#pragma unroll                          // order spreads the 16-bank qq stride
                for (int e = 0; e < 4; ++e) {
                    int er = (e + qq) & 3;
                    int iv = (qq << 2) + er - 2;
                    if ((unsigned)iv < (unsigned)VC)
                        s_vw[row - 2][iv] = make_float4(rr[er], gg[er], bb[er], kk[er]);
                }
            }
        }
    }
    __syncthreads();

    // ---- stage 3: vertical 5-sum -> variance -> weight. 2-col x 4-row tasks,
    // sliding vertical sums: 8 b128 reads -> 8 weights (1.0 reads/output, was
    // 1.5). 162 tasks = 9 row-quads x 18 col-pairs, SINGLE pass.
    if (tid < 162) {
        int j4r = tid / 18, q = tid - j4r * 18;
        int j4  = j4r << 2;                     // rows j4 .. j4+3
        int c   = q << 1;                       // cols c, c+1
        int g0  = x0 - 2 + c;
        bool okx = (g0 >= 0) && (g0 + 1 <= W - 1);
        bool oky = (y0 - 2 + j4 >= 0) && (y0 - 2 + j4 + 3 <= H - 1);
        if (okx && oky) {                       // fast: all 8 centers unclamped
            float4 r0 = *(const float4*)&s_su[j4 + 0][c];
            float4 r1 = *(const float4*)&s_su[j4 + 1][c];
            float4 r2 = *(const float4*)&s_su[j4 + 2][c];
            float4 r3 = *(const float4*)&s_su[j4 + 3][c];
            float4 r4 = *(const float4*)&s_su[j4 + 4][c];
            float4 r5 = *(const float4*)&s_su[j4 + 5][c];
            float4 r6 = *(const float4*)&s_su[j4 + 6][c];
            float4 r7 = *(const float4*)&s_su[j4 + 7][c];
            float sx = (((r0.x + r1.x) + (r2.x + r3.x)) + r4.x);
            float sy = (((r0.y + r1.y) + (r2.y + r3.y)) + r4.y);
            float sz = (((r0.z + r1.z) + (r2.z + r3.z)) + r4.z);
            float sw = (((r0.w + r1.w) + (r2.w + r3.w)) + r4.w);
#pragma unroll
            for (int jj = 0; jj < 4; ++jj) {
                {
                    float mean = sx * 0.04f, msq = sy * 0.04f;
                    float var  = fabsf(msq - mean * mean);
                    s_vw[j4 + jj][c].w = __expf(-var * 64.0f * s_vw[j4 + jj][c].w);
                }
                {
                    float mean = sz * 0.04f, msq = sw * 0.04f;
                    float var  = fabsf(msq - mean * mean);
                    s_vw[j4 + jj][c + 1].w = __expf(-var * 64.0f * s_vw[j4 + jj][c + 1].w);
                }
                if (jj < 3) {                   // slide window down one row
                    const float4 rl = (jj == 0) ? r0 : (jj == 1) ? r1 : r2;
                    const float4 rh = (jj == 0) ? r5 : (jj == 1) ? r6 : r7;
                    sx += rh.x - rl.x;  sy += rh.y - rl.y;
                    sz += rh.z - rl.z;  sw += rh.w - rl.w;
                }
            }
        } else {                                // border: per-output scalar
#pragma unroll
            for (int jj = 0; jj < 4; ++jj) {
                int j2 = j4 + jj;
                int gyc = min(max(y0 - 2 + j2, 0), H - 1);
                int js  = gyc - y0 + 2;
#pragma unroll
                for (int e = 0; e < 2; ++e) {
                    int is = min(max(g0 + e, 0), W - 1) - x0 + 2;
                    float ss = 0.f, sq = 0.f;
#pragma unroll
                    for (int r = 0; r < 5; ++r) {
                        float2 v = s_su[js + r][is];
                        ss += v.x; sq += v.y;
                    }
                    float mean = ss * 0.04f, msq = sq * 0.04f;
                    float var  = fabsf(msq - mean * mean);
                    s_vw[j2][c + e].w = __expf(-var * 64.0f * s_vw[j2][c + e].w);
                }
            }
        }
    }
    __syncthreads();

    // ---- spatial-falloff constants (late, short live ranges) ----
    float t1[4], t4[4];
#pragma unroll
    for (int p = 0; p < 4; ++p) {
        float t = __expf(-2.56f * (1.0f - kc[p]));   // t^(dx^2+dy^2) base
        t1[p] = t;
        t4[p] = (t * t) * (t * t);
    }

    // ---- stage 4: 25-tap filter; factorized row sums shared across 4 px ----
    float accR[4], accG[4], accB[4], accW[4];
    float ctrR[4], ctrG[4], ctrB[4];
#pragma unroll
    for (int p = 0; p < 4; ++p) { accR[p] = accG[p] = accB[p] = accW[p] = 0.f; }

#pragma unroll
    for (int r = 0; r < 8; ++r) {
        const float4* row = &s_vw[pr0 + r][tx];      // single base, imm offsets
        float4 a0 = row[0], a1 = row[1], a2 = row[2], a3 = row[3], a4 = row[4];
        // partial sums by |dx|: S0 (dx=0), S1 (|dx|=1), S2 (|dx|=2)
        float S0w = a2.w;
        float S0x = a2.w * a2.x, S0y = a2.w * a2.y, S0z = a2.w * a2.z;
        float S1w = a1.w + a3.w;
        float S1x = a1.w * a1.x + a3.w * a3.x;
        float S1y = a1.w * a1.y + a3.w * a3.y;
        float S1z = a1.w * a1.z + a3.w * a3.z;
        float S2w = a0.w + a4.w;
        float S2x = a0.w * a0.x + a4.w * a4.x;
        float S2y = a0.w * a0.y + a4.w * a4.y;
        float S2z = a0.w * a0.z + a4.w * a4.z;
#pragma unroll
        for (int p = 0; p < 4; ++p) {
            const int dy = r - 2 - p;                // compile-time after unroll
            if (dy < -2 || dy > 2) continue;
            const int ady = dy < 0 ? -dy : dy;
            float rw = S0w + t1[p] * S1w + t4[p] * S2w;
            float rx = S0x + t1[p] * S1x + t4[p] * S2x;
            float ry = S0y + t1[p] * S1y + t4[p] * S2y;
            float rz = S0z + t1[p] * S1z + t4[p] * S2z;
            if (ady == 0) {                          // center row: capture rgb
                ctrR[p] = a2.x; ctrG[p] = a2.y; ctrB[p] = a2.z;
                accR[p] += rx; accG[p] += ry; accB[p] += rz; accW[p] += rw;
            } else {
                float rf = (ady == 1) ? t1[p] : t4[p];
                accR[p] += rf * rx; accG[p] += rf * ry;
                accB[p] += rf * rz; accW[p] += rf * rw;
            }
        }
    }

    float* __restrict__ oR = out + ((size_t)(3*n + 0) << 20);
    float* __restrict__ oG = out + ((size_t)(3*n + 1) << 20);
    float* __restrict__ oB = out + ((size_t)(3*n + 2) << 20);
#pragma unroll
    for (int p = 0; p < 4; ++p) {
        float cb = 16.0f + kc[p] * (0.001f - 16.0f); // center boost
        accR[p] += cb * ctrR[p];
        accG[p] += cb * ctrG[p];
        accB[p] += cb * ctrB[p];
        accW[p] += cb;
        float inv = __builtin_amdgcn_rcpf(accW[p]);
        int off = ((y0 + pr0 + p) << 10) + gx;
        oR[off] = ctrR[p] + kc[p] * (accR[p] * inv - ctrR[p]);
        oG[off] = ctrG[p] + kc[p] * (accG[p] * inv - ctrG[p]);
        oB[off] = ctrB[p] + kc[p] * (accB[p] * inv - ctrB[p]);
    }
}

extern "C" void kernel_launch(void* const* d_in, const int* in_sizes, int n_in,
                              void* d_out, int out_size, void* d_ws, size_t ws_size,
                              hipStream_t stream) {
    const float* inp = (const float*)d_in[0];
    float* out = (float*)d_out;
    hipLaunchKernelGGL(kuwahara_kernel, dim3(4096), dim3(256), 0, stream, inp, out);
}